// Round 7
// baseline (249.417 us; speedup 1.0000x reference)
//
#include <hip/hip_runtime.h>
#include <cstdint>
#include <cstddef>

#define N_ANCH 25200
#define NB0 19200
#define NB1 24000
#define TOPK_N 4096
#define CONF_T 0.001
#define NMS_T 0.6
#define IMGS 640.0
#define NBINS 4096       // fp32 bits >> 18 (score in [0,1] -> bin <= 4064)

typedef unsigned long long u64;

struct WS {
  alignas(64) double sc[N_ANCH];       // masked score (sc or -1.0)
  alignas(64) double box[N_ANCH][4];   // clipped normalized boxes, fp64
  alignas(64) int    cls[N_ANCH];
  alignas(64) int    binv[N_ANCH];     // score bin per anchor
  alignas(64) int    sid[N_ANCH];      // bin-grouped compacted anchor ids
  alignas(64) double ssc[N_ANCH];      // bin-grouped compacted scores
  alignas(64) int    sst[N_ANCH];      // bin segment start of this slot
  alignas(64) int    sen[N_ANCH];      // bin segment end of this slot
  int    m_count;
  int    done;                          // completion counter for iou->nms handoff
  alignas(64) double tbox[TOPK_N][4];
  alignas(64) double tarea[TOPK_N];
  alignas(64) double tsc[TOPK_N];
  alignas(64) int    tcls[TOPK_N];
  alignas(64) u64    supT[TOPK_N * 64]; // supT[i*64+w] valid only for w <= i>>6
  alignas(64) u64    hasSup[64];        // bit i of word (i>>6): row i has >=1 suppressor
};

__device__ __forceinline__ double dsigmoid(double x) { return 1.0 / (1.0 + exp(-x)); }

__device__ __forceinline__ int score_bin(double sc) {
  if (sc < 0.0) return 0;                          // masked
  return (int)(__float_as_uint((float)sc) >> 18);  // monotone for positive floats
}

// 4 lanes per anchor: lane r of a team handles classes c ≡ r (mod 4).
__global__ void k_decode(const float* __restrict__ ps, const float* __restrict__ pm,
                         const float* __restrict__ pl, const float* __restrict__ anch,
                         WS* __restrict__ ws) {
  int tid = blockIdx.x * 256 + threadIdx.x;
  if (tid < 64) ws->hasSup[tid] = 0ull;   // zero for k_iou's atomicOr
  if (tid == 64) ws->done = 0;            // zero completion counter
  int a = tid >> 2;
  int r = tid & 3;
  if (a >= N_ANCH) return;   // team-uniform (4-aligned)
  const float* p; int W, base, lvl; double stride;
  if (a < NB0)      { p = ps; W = 80; base = 0;   lvl = 0; stride = 8.0; }
  else if (a < NB1) { p = pm; W = 40; base = NB0; lvl = 1; stride = 16.0; }
  else              { p = pl; W = 20; base = NB1; lvl = 2; stride = 32.0; }
  int e = a - base;
  int pos = e / 3;
  int k = e - 3 * pos;
  int HW = W * W;

  // class max/argmax + softmax denom, 20 classes per lane
  const float* pc = p + (size_t)(3 + k * 80) * HW + pos;
  double m = -1e300, ssum = 0.0; int am = 0;
  for (int t = 0; t < 20; ++t) {
    int c = r + 4 * t;
    double v = (double)pc[(size_t)c * HW];
    ssum += exp(v);
    if (v > m) { m = v; am = c; }  // strict > keeps first occurrence per lane
  }
  // team reduction (lanes r^1, r^2 are in the same 4-lane group within the wave)
  for (int off = 1; off <= 2; off <<= 1) {
    double om = __shfl_xor(m, off);
    int oam   = __shfl_xor(am, off);
    double os = __shfl_xor(ssum, off);
    ssum += os;
    if (om > m || (om == m && oam < am)) { m = om; am = oam; }  // first-max tie-break
  }

  if (r == 0) {
    double sobj = dsigmoid((double)p[(size_t)k * HW + pos]);
    double sc = sobj * (exp(m) / ssum);

    int x = pos % W, y = pos / W;
    const float* pr = p + (size_t)(243 + k * 4) * HW + pos;
    double tx = (double)pr[0];
    double ty = (double)pr[(size_t)HW];
    double tw = (double)pr[(size_t)2 * HW];
    double th = (double)pr[(size_t)3 * HW];
    double cx = (dsigmoid(tx) + (double)x) * stride;
    double cy = (dsigmoid(ty) + (double)y) * stride;
    double aw = (double)anch[lvl * 6 + k * 2 + 0];
    double ah = (double)anch[lvl * 6 + k * 2 + 1];
    double bw = exp(tw) * aw;
    double bh = exp(th) * ah;
    double x1 = fmin(fmax((cx - 0.5 * bw) / IMGS, 0.0), 1.0);
    double y1 = fmin(fmax((cy - 0.5 * bh) / IMGS, 0.0), 1.0);
    double x2 = fmin(fmax((cx + 0.5 * bw) / IMGS, 0.0), 1.0);
    double y2 = fmin(fmax((cy + 0.5 * bh) / IMGS, 0.0), 1.0);

    ws->box[a][0] = x1; ws->box[a][1] = y1;
    ws->box[a][2] = x2; ws->box[a][3] = y2;
    ws->cls[a] = am;
    double scm = (sc >= CONF_T) ? sc : -1.0;
    ws->sc[a] = scm;
    ws->binv[a] = score_bin(scm);
  }
}

// single block: LDS hist -> t_bin = max b with S(b)=#{bin>=b} >= TOPK_N,
// then BIN-GROUPED compaction: slot = off0[bin] + within-bin counter.
// Global rank of a slot later = sst + exact rank within its bin segment.
__global__ void __launch_bounds__(1024) k_selcomp(WS* __restrict__ ws) {
  __shared__ int hist[NBINS];   // 16 KB
  __shared__ int off0[NBINS];   // 16 KB  (count of elements in strictly higher bins)
  __shared__ int cnt[NBINS];    // 16 KB  (within-bin compaction counters)
  __shared__ int part[1024];
  __shared__ int s_tbin;
  int t = threadIdx.x;
  for (int i = t; i < NBINS; i += 1024) { hist[i] = 0; cnt[i] = 0; }
  __syncthreads();
  for (int i = t; i < N_ANCH; i += 1024) atomicAdd(&hist[ws->binv[i]], 1);
  __syncthreads();
  const int CH = NBINS / 1024;  // 4 reversed bins per thread
  int sum = 0;
  for (int rr = 0; rr < CH; ++rr) sum += hist[NBINS - 1 - (t * CH + rr)];
  part[t] = sum;
  __syncthreads();
  for (int off = 1; off < 1024; off <<= 1) {
    int v = (t >= off) ? part[t - off] : 0;
    __syncthreads();
    part[t] += v;
    __syncthreads();
  }
  int cum = part[t] - sum;  // count in bins above this thread's chunk
  for (int rr = 0; rr < CH; ++rr) {
    int b = NBINS - 1 - (t * CH + rr);
    int h = hist[b];
    off0[b] = cum;
    int prev = cum;
    cum += h;
    if (prev < TOPK_N && cum >= TOPK_N) { s_tbin = b; ws->m_count = cum; }  // unique
  }
  __syncthreads();
  int tbin = s_tbin;
  for (int i = t; i < N_ANCH; i += 1024) {
    int b = ws->binv[i];
    if (b >= tbin) {
      int w = atomicAdd(&cnt[b], 1);
      int slot = off0[b] + w;
      ws->sid[slot] = i;
      ws->ssc[slot] = ws->sc[i];
      ws->sst[slot] = off0[b];
      ws->sen[slot] = off0[b] + hist[b];
    }
  }
}

// rank = sst + #{j in own bin segment : sc_j > sc_i or (sc_j==sc_i && aj<ai)};
// then scatter directly (ranks are distinct, cover 0..m-1).
__global__ void k_rankscatter(WS* __restrict__ ws, float* __restrict__ out) {
  int m = ws->m_count;
  if ((int)blockIdx.x * 256 >= m) return;   // block-uniform exit
  int i = blockIdx.x * 256 + threadIdx.x;
  if (i >= m) return;
  int ai = ws->sid[i];
  double si = ws->ssc[i];
  int st = ws->sst[i], en = ws->sen[i];
  int r = st;
  for (int j = st; j < en; ++j) {
    double s = ws->ssc[j];
    r += (int)((s > si) | ((s == si) & (ws->sid[j] < ai)));
  }
  if (r < TOPK_N) {
    double b0 = ws->box[ai][0], b1 = ws->box[ai][1];
    double b2 = ws->box[ai][2], b3 = ws->box[ai][3];
    int    c  = ws->cls[ai];
    ws->tbox[r][0] = b0; ws->tbox[r][1] = b1;
    ws->tbox[r][2] = b2; ws->tbox[r][3] = b3;
    ws->tarea[r] = (b2 - b0) * (b3 - b1);
    ws->tsc[r] = si;
    ws->tcls[r] = c;
    out[r * 4 + 0] = (float)b0;
    out[r * 4 + 1] = (float)b1;
    out[r * 4 + 2] = (float)b2;
    out[r * 4 + 3] = (float)b3;
    out[4 * TOPK_N + r] = (float)si;
    out[5 * TOPK_N + r] = (float)c;
  }
}

struct IouSmem { double jb[64][5]; int jc[64]; };
struct NmsSmem { u64 hs[64]; int lst[TOPK_N]; };

// Lower-triangle suppression tiles; the LAST block to finish runs the greedy
// NMS scan inline (device-scope counter + threadfence release/acquire).
__global__ void __launch_bounds__(256) k_iou(WS* __restrict__ ws, float* __restrict__ out) {
  __shared__ union { IouSmem iou; NmsSmem nms; } sm;
  __shared__ int s_last;
  int t = threadIdx.x;
  int bx = blockIdx.x;
  int ti = bx >> 6, w = bx & 63;
  int i0 = ti * 256, jbase = w * 64;

  if (jbase < i0 + 256) {      // block-uniform: tile intersects lower triangle
    if (t < 64) {
      int j = jbase + t;
      sm.iou.jb[t][0] = ws->tbox[j][0];
      sm.iou.jb[t][1] = ws->tbox[j][1];
      sm.iou.jb[t][2] = ws->tbox[j][2];
      sm.iou.jb[t][3] = ws->tbox[j][3];
      sm.iou.jb[t][4] = ws->tarea[j];
      sm.iou.jc[t] = ws->tcls[j];
    }
    __syncthreads();
    int i = i0 + t;
    double x1 = ws->tbox[i][0], y1 = ws->tbox[i][1];
    double x2 = ws->tbox[i][2], y2 = ws->tbox[i][3];
    double ai = ws->tarea[i];
    int ci = ws->tcls[i];
    u64 bits = 0;
    for (int u = 0; u < 64; ++u) {
      double xx1 = fmax(x1, sm.iou.jb[u][0]);
      double yy1 = fmax(y1, sm.iou.jb[u][1]);
      double xx2 = fmin(x2, sm.iou.jb[u][2]);
      double yy2 = fmin(y2, sm.iou.jb[u][3]);
      double iw = fmax(1e-28, xx2 - xx1);
      double ih = fmax(1e-28, yy2 - yy1);
      double inter = iw * ih;
      double denom = ai + sm.iou.jb[u][4] - inter + 1e-14;
      bool sup = (sm.iou.jc[u] == ci) && (inter > NMS_T * denom) && ((jbase + u) < i);
      bits |= ((u64)sup) << u;
    }
    ws->supT[(size_t)i * 64 + w] = bits;
    if (bits) atomicOr(&ws->hasSup[i >> 6], 1ull << (i & 63));
    __syncthreads();
  }

  // completion handshake (ALL 1024 blocks participate)
  __threadfence();   // release: supT/hasSup stores visible before count
  if (t == 0) {
    int old = atomicAdd(&ws->done, 1);
    s_last = (old == 16 * 64 - 1);
  }
  __syncthreads();
  if (!s_last) return;
  __threadfence();   // acquire: see all other blocks' stores

  // ---- greedy NMS over contested candidates (single wave of this block) ----
  u64 validw = 0, keepw = 0;
  if (t < 64) {
    const double4* tp = (const double4*)(ws->tsc + t * 64);
    for (int q = 0; q < 16; ++q) {
      double4 v = tp[q];
      validw |= ((u64)(v.x >= CONF_T)) << (q * 4 + 0);
      validw |= ((u64)(v.y >= CONF_T)) << (q * 4 + 1);
      validw |= ((u64)(v.z >= CONF_T)) << (q * 4 + 2);
      validw |= ((u64)(v.w >= CONF_T)) << (q * 4 + 3);
    }
    u64 hasw = ws->hasSup[t];
    keepw = validw & ~hasw;   // bulk-keep uncontested valid candidates
    sm.nms.hs[t] = hasw;
  }
  __syncthreads();
  int K = 0;
  if (t < 64) {
    for (int l = 0; l < 64; ++l) {
      u64 wd = sm.nms.hs[l];
      while (wd) {
        int b = __builtin_ctzll(wd);
        wd &= wd - 1;
        if (t == 0) sm.nms.lst[K] = l * 64 + b;
        ++K;
      }
    }
  }
  __syncthreads();
  if (t < 64) {
    const u64* ST = ws->supT;
    const int* lst = sm.nms.lst;
    int IA[16], IB[16];
    u64 A[16], B[16];
    // masked row load: words w > i>>6 were never written (upper triangle) -> 0
#define LOADR(DST, IDX, OK) { DST = 0ull; if ((OK) && t <= ((IDX) >> 6)) DST = ST[(size_t)(IDX) * 64 + t]; }
#pragma unroll
    for (int r = 0; r < 16; ++r) { IA[r] = (r < K) ? lst[r] : 0; LOADR(A[r], IA[r], r < K) }

    for (int base = 0; base < K; base += 32) {
#pragma unroll
      for (int r = 0; r < 16; ++r) { IB[r] = (base + 16 + r < K) ? lst[base + 16 + r] : 0; LOADR(B[r], IB[r], base + 16 + r < K) }
#pragma unroll
      for (int r = 0; r < 16; ++r) {
        if (base + r < K) {
          int i = IA[r];
          u64 bal = __ballot((keepw & A[r]) != 0ull);
          if (t == (i >> 6) && bal == 0ull && ((validw >> (i & 63)) & 1ull))
            keepw |= 1ull << (i & 63);
        }
      }
#pragma unroll
      for (int r = 0; r < 16; ++r) { IA[r] = (base + 32 + r < K) ? lst[base + 32 + r] : 0; LOADR(A[r], IA[r], base + 32 + r < K) }
#pragma unroll
      for (int r = 0; r < 16; ++r) {
        if (base + 16 + r < K) {
          int i = IB[r];
          u64 bal = __ballot((keepw & B[r]) != 0ull);
          if (t == (i >> 6) && bal == 0ull && ((validw >> (i & 63)) & 1ull))
            keepw |= 1ull << (i & 63);
        }
      }
    }
#undef LOADR
    for (int b = 0; b < 64; ++b)
      out[6 * TOPK_N + t * 64 + b] = (float)((keepw >> b) & 1ull);
  }
}

extern "C" void kernel_launch(void* const* d_in, const int* in_sizes, int n_in,
                              void* d_out, int out_size, void* d_ws, size_t ws_size,
                              hipStream_t stream) {
  const float* ps   = (const float*)d_in[0];
  const float* pm   = (const float*)d_in[1];
  const float* pl   = (const float*)d_in[2];
  const float* anch = (const float*)d_in[3];
  float* out = (float*)d_out;
  WS* ws = (WS*)d_ws;

  dim3 blk(256);
  k_decode     <<<dim3((N_ANCH * 4 + 255) / 256), blk, 0, stream>>>(ps, pm, pl, anch, ws);
  k_selcomp    <<<dim3(1), dim3(1024), 0, stream>>>(ws);
  k_rankscatter<<<dim3((N_ANCH + 255) / 256), blk, 0, stream>>>(ws, out);
  k_iou        <<<dim3(16 * 64), blk, 0, stream>>>(ws, out);
}

// Round 8
// 160.637 us; speedup vs baseline: 1.5527x; 1.5527x over previous
//
#include <hip/hip_runtime.h>
#include <cstdint>
#include <cstddef>

#define N_ANCH 25200
#define NB0 19200
#define NB1 24000
#define TOPK_N 4096
#define CONF_T 0.001
#define NMS_T 0.6
#define IMGS 640.0
#define NBINS 4096       // fp32 bits >> 18 (score in [0,1] -> bin <= 4064)
#define LTILES 544       // lower-triangle (ti,w) tiles: sum_{ti=0}^{15} (4*ti+4)

typedef unsigned long long u64;

struct WS {
  alignas(64) double sc[N_ANCH];       // masked score (sc or -1.0)
  alignas(64) double box[N_ANCH][4];   // clipped normalized boxes, fp64
  alignas(64) int    cls[N_ANCH];
  alignas(64) int    binv[N_ANCH];     // score bin per anchor
  alignas(64) int    sid[N_ANCH];      // bin-grouped compacted anchor ids
  alignas(64) double ssc[N_ANCH];      // bin-grouped compacted scores
  alignas(64) int    sst[N_ANCH];      // bin segment start of this slot
  alignas(64) int    sen[N_ANCH];      // bin segment end of this slot
  int    m_count;
  alignas(64) double tbox[TOPK_N][4];
  alignas(64) double tarea[TOPK_N];
  alignas(64) double tsc[TOPK_N];
  alignas(64) int    tcls[TOPK_N];
  alignas(64) u64    supT[TOPK_N * 64]; // supT[i*64+w] written only for w <= i>>6 (rest stays poison; k_nms masks)
  alignas(64) u64    hasSup[64];        // bit i of word (i>>6): row i has >=1 suppressor
};

__device__ __forceinline__ double dsigmoid(double x) { return 1.0 / (1.0 + exp(-x)); }

__device__ __forceinline__ int score_bin(double sc) {
  if (sc < 0.0) return 0;                          // masked
  return (int)(__float_as_uint((float)sc) >> 18);  // monotone for positive floats
}

// 4 lanes per anchor: lane r of a team handles classes c ≡ r (mod 4).
__global__ void k_decode(const float* __restrict__ ps, const float* __restrict__ pm,
                         const float* __restrict__ pl, const float* __restrict__ anch,
                         WS* __restrict__ ws) {
  int tid = blockIdx.x * 256 + threadIdx.x;
  if (tid < 64) ws->hasSup[tid] = 0ull;   // zero for k_iou's atomicOr
  int a = tid >> 2;
  int r = tid & 3;
  if (a >= N_ANCH) return;   // team-uniform (4-aligned)
  const float* p; int W, base, lvl; double stride;
  if (a < NB0)      { p = ps; W = 80; base = 0;   lvl = 0; stride = 8.0; }
  else if (a < NB1) { p = pm; W = 40; base = NB0; lvl = 1; stride = 16.0; }
  else              { p = pl; W = 20; base = NB1; lvl = 2; stride = 32.0; }
  int e = a - base;
  int pos = e / 3;
  int k = e - 3 * pos;
  int HW = W * W;

  // class max/argmax + softmax denom, 20 classes per lane
  const float* pc = p + (size_t)(3 + k * 80) * HW + pos;
  double m = -1e300, ssum = 0.0; int am = 0;
  for (int t = 0; t < 20; ++t) {
    int c = r + 4 * t;
    double v = (double)pc[(size_t)c * HW];
    ssum += exp(v);
    if (v > m) { m = v; am = c; }  // strict > keeps first occurrence per lane
  }
  // team reduction (lanes r^1, r^2 are in the same 4-lane group within the wave)
  for (int off = 1; off <= 2; off <<= 1) {
    double om = __shfl_xor(m, off);
    int oam   = __shfl_xor(am, off);
    double os = __shfl_xor(ssum, off);
    ssum += os;
    if (om > m || (om == m && oam < am)) { m = om; am = oam; }  // first-max tie-break
  }

  if (r == 0) {
    double sobj = dsigmoid((double)p[(size_t)k * HW + pos]);
    double sc = sobj * (exp(m) / ssum);

    int x = pos % W, y = pos / W;
    const float* pr = p + (size_t)(243 + k * 4) * HW + pos;
    double tx = (double)pr[0];
    double ty = (double)pr[(size_t)HW];
    double tw = (double)pr[(size_t)2 * HW];
    double th = (double)pr[(size_t)3 * HW];
    double cx = (dsigmoid(tx) + (double)x) * stride;
    double cy = (dsigmoid(ty) + (double)y) * stride;
    double aw = (double)anch[lvl * 6 + k * 2 + 0];
    double ah = (double)anch[lvl * 6 + k * 2 + 1];
    double bw = exp(tw) * aw;
    double bh = exp(th) * ah;
    double x1 = fmin(fmax((cx - 0.5 * bw) / IMGS, 0.0), 1.0);
    double y1 = fmin(fmax((cy - 0.5 * bh) / IMGS, 0.0), 1.0);
    double x2 = fmin(fmax((cx + 0.5 * bw) / IMGS, 0.0), 1.0);
    double y2 = fmin(fmax((cy + 0.5 * bh) / IMGS, 0.0), 1.0);

    ws->box[a][0] = x1; ws->box[a][1] = y1;
    ws->box[a][2] = x2; ws->box[a][3] = y2;
    ws->cls[a] = am;
    double scm = (sc >= CONF_T) ? sc : -1.0;
    ws->sc[a] = scm;
    ws->binv[a] = score_bin(scm);
  }
}

// single block: LDS hist -> t_bin = max b with S(b)=#{bin>=b} >= TOPK_N,
// then BIN-GROUPED compaction: slot = off0[bin] + within-bin counter.
// Global rank of a slot later = sst + exact rank within its bin segment.
__global__ void __launch_bounds__(1024) k_selcomp(WS* __restrict__ ws) {
  __shared__ int hist[NBINS];   // 16 KB
  __shared__ int off0[NBINS];   // 16 KB  (count of elements in strictly higher bins)
  __shared__ int cnt[NBINS];    // 16 KB  (within-bin compaction counters)
  __shared__ int part[1024];
  __shared__ int s_tbin;
  int t = threadIdx.x;
  for (int i = t; i < NBINS; i += 1024) { hist[i] = 0; cnt[i] = 0; }
  __syncthreads();
  for (int i = t; i < N_ANCH; i += 1024) atomicAdd(&hist[ws->binv[i]], 1);
  __syncthreads();
  const int CH = NBINS / 1024;  // 4 reversed bins per thread
  int sum = 0;
  for (int rr = 0; rr < CH; ++rr) sum += hist[NBINS - 1 - (t * CH + rr)];
  part[t] = sum;
  __syncthreads();
  for (int off = 1; off < 1024; off <<= 1) {
    int v = (t >= off) ? part[t - off] : 0;
    __syncthreads();
    part[t] += v;
    __syncthreads();
  }
  int cum = part[t] - sum;  // count in bins above this thread's chunk
  for (int rr = 0; rr < CH; ++rr) {
    int b = NBINS - 1 - (t * CH + rr);
    int h = hist[b];
    off0[b] = cum;
    int prev = cum;
    cum += h;
    if (prev < TOPK_N && cum >= TOPK_N) { s_tbin = b; ws->m_count = cum; }  // unique
  }
  __syncthreads();
  int tbin = s_tbin;
  for (int i = t; i < N_ANCH; i += 1024) {
    int b = ws->binv[i];
    if (b >= tbin) {
      int w = atomicAdd(&cnt[b], 1);
      int slot = off0[b] + w;
      ws->sid[slot] = i;
      ws->ssc[slot] = ws->sc[i];
      ws->sst[slot] = off0[b];
      ws->sen[slot] = off0[b] + hist[b];
    }
  }
}

// rank = sst + #{j in own bin segment : sc_j > sc_i or (sc_j==sc_i && aj<ai)};
// then scatter directly (ranks are distinct, cover 0..m-1).
__global__ void k_rankscatter(WS* __restrict__ ws, float* __restrict__ out) {
  int m = ws->m_count;
  if ((int)blockIdx.x * 256 >= m) return;   // block-uniform exit
  int i = blockIdx.x * 256 + threadIdx.x;
  if (i >= m) return;
  int ai = ws->sid[i];
  double si = ws->ssc[i];
  int st = ws->sst[i], en = ws->sen[i];
  int r = st;
  for (int j = st; j < en; ++j) {
    double s = ws->ssc[j];
    r += (int)((s > si) | ((s == si) & (ws->sid[j] < ai)));
  }
  if (r < TOPK_N) {
    double b0 = ws->box[ai][0], b1 = ws->box[ai][1];
    double b2 = ws->box[ai][2], b3 = ws->box[ai][3];
    int    c  = ws->cls[ai];
    ws->tbox[r][0] = b0; ws->tbox[r][1] = b1;
    ws->tbox[r][2] = b2; ws->tbox[r][3] = b3;
    ws->tarea[r] = (b2 - b0) * (b3 - b1);
    ws->tsc[r] = si;
    ws->tcls[r] = c;
    out[r * 4 + 0] = (float)b0;
    out[r * 4 + 1] = (float)b1;
    out[r * 4 + 2] = (float)b2;
    out[r * 4 + 3] = (float)b3;
    out[4 * TOPK_N + r] = (float)si;
    out[5 * TOPK_N + r] = (float)c;
  }
}

// Lower-triangle suppression tiles ONLY (544 blocks). Tile (ti,w): rows
// i in [ti*256, ti*256+256), cols j in [w*64, w*64+64), w <= 4*ti+3.
// supT[i*64+w] bit u: j=w*64+u suppresses i (same class, iou>0.6, j<i).
__global__ void __launch_bounds__(256) k_iou(WS* __restrict__ ws) {
  __shared__ double jb[64][5];
  __shared__ int jc[64];
  int t = threadIdx.x;
  int bx = blockIdx.x;
  // invert triangular numbering: tiles before ti = 2*ti*(ti+1)
  int ti = (int)((sqrtf(2.0f * (float)bx + 1.0f) - 1.0f) * 0.5f);
  while (2 * (ti + 1) * (ti + 2) <= bx) ++ti;
  while (2 * ti * (ti + 1) > bx) --ti;
  int w = bx - 2 * ti * (ti + 1);
  int i0 = ti * 256, jbase = w * 64;

  if (t < 64) {
    int j = jbase + t;
    jb[t][0] = ws->tbox[j][0];
    jb[t][1] = ws->tbox[j][1];
    jb[t][2] = ws->tbox[j][2];
    jb[t][3] = ws->tbox[j][3];
    jb[t][4] = ws->tarea[j];
    jc[t] = ws->tcls[j];
  }
  __syncthreads();
  int i = i0 + t;
  double x1 = ws->tbox[i][0], y1 = ws->tbox[i][1];
  double x2 = ws->tbox[i][2], y2 = ws->tbox[i][3];
  double ai = ws->tarea[i];
  int ci = ws->tcls[i];
  u64 bits = 0;
  for (int u = 0; u < 64; ++u) {
    double xx1 = fmax(x1, jb[u][0]);
    double yy1 = fmax(y1, jb[u][1]);
    double xx2 = fmin(x2, jb[u][2]);
    double yy2 = fmin(y2, jb[u][3]);
    double iw = fmax(1e-28, xx2 - xx1);
    double ih = fmax(1e-28, yy2 - yy1);
    double inter = iw * ih;
    double denom = ai + jb[u][4] - inter + 1e-14;
    bool sup = (jc[u] == ci) && (inter > NMS_T * denom) && ((jbase + u) < i);
    bits |= ((u64)sup) << u;
  }
  ws->supT[(size_t)i * 64 + w] = bits;
  if (bits) atomicOr(&ws->hasSup[i >> 6], 1ull << (i & 63));
}

// single-wave greedy scan over CONTESTED candidates only. Row loads are
// UNCONDITIONAL (batched prefetch); upper-triangle words contain workspace
// poison and are masked out per-lane AFTER the load (lane <= i>>6).
__global__ void __launch_bounds__(64) k_nms(const WS* __restrict__ ws, float* __restrict__ out) {
  __shared__ u64 hsArr[64];
  __shared__ int lst[TOPK_N];
  int lane = threadIdx.x;

  u64 validw = 0;
  const double4* tp = (const double4*)(ws->tsc + lane * 64);
  for (int q = 0; q < 16; ++q) {
    double4 v = tp[q];
    validw |= ((u64)(v.x >= CONF_T)) << (q * 4 + 0);
    validw |= ((u64)(v.y >= CONF_T)) << (q * 4 + 1);
    validw |= ((u64)(v.z >= CONF_T)) << (q * 4 + 2);
    validw |= ((u64)(v.w >= CONF_T)) << (q * 4 + 3);
  }

  u64 hasw = ws->hasSup[lane];
  u64 keepw = validw & ~hasw;   // bulk-keep uncontested valid candidates
  hsArr[lane] = hasw;
  __syncthreads();

  int K = 0;
  for (int l = 0; l < 64; ++l) {
    u64 w = hsArr[l];
    while (w) {
      int b = __builtin_ctzll(w);
      w &= w - 1;
      if (lane == 0) lst[K] = l * 64 + b;
      ++K;
    }
  }
  __syncthreads();

  const u64* ST = ws->supT;
  int IA[16], IB[16];
  u64 A[16], B[16];

  // post-load mask: lane holds valid word only if lane <= i>>6
#define RB(BUF, IDX) ((lane <= ((IDX) >> 6)) ? BUF : 0ull)

#pragma unroll
  for (int r = 0; r < 16; ++r) IA[r] = (r < K) ? lst[r] : 0;
#pragma unroll
  for (int r = 0; r < 16; ++r) A[r] = (r < K) ? ST[(size_t)IA[r] * 64 + lane] : 0ull;

  for (int base = 0; base < K; base += 32) {
#pragma unroll
    for (int r = 0; r < 16; ++r) IB[r] = (base + 16 + r < K) ? lst[base + 16 + r] : 0;
#pragma unroll
    for (int r = 0; r < 16; ++r) B[r] = (base + 16 + r < K) ? ST[(size_t)IB[r] * 64 + lane] : 0ull;
#pragma unroll
    for (int r = 0; r < 16; ++r) {
      if (base + r < K) {
        int i = IA[r];
        u64 bal = __ballot((keepw & RB(A[r], i)) != 0ull);
        if (lane == (i >> 6) && bal == 0ull && ((validw >> (i & 63)) & 1ull))
          keepw |= 1ull << (i & 63);
      }
    }
#pragma unroll
    for (int r = 0; r < 16; ++r) IA[r] = (base + 32 + r < K) ? lst[base + 32 + r] : 0;
#pragma unroll
    for (int r = 0; r < 16; ++r) A[r] = (base + 32 + r < K) ? ST[(size_t)IA[r] * 64 + lane] : 0ull;
#pragma unroll
    for (int r = 0; r < 16; ++r) {
      if (base + 16 + r < K) {
        int i = IB[r];
        u64 bal = __ballot((keepw & RB(B[r], i)) != 0ull);
        if (lane == (i >> 6) && bal == 0ull && ((validw >> (i & 63)) & 1ull))
          keepw |= 1ull << (i & 63);
      }
    }
  }
#undef RB

  for (int b = 0; b < 64; ++b)
    out[6 * TOPK_N + lane * 64 + b] = (float)((keepw >> b) & 1ull);
}

extern "C" void kernel_launch(void* const* d_in, const int* in_sizes, int n_in,
                              void* d_out, int out_size, void* d_ws, size_t ws_size,
                              hipStream_t stream) {
  const float* ps   = (const float*)d_in[0];
  const float* pm   = (const float*)d_in[1];
  const float* pl   = (const float*)d_in[2];
  const float* anch = (const float*)d_in[3];
  float* out = (float*)d_out;
  WS* ws = (WS*)d_ws;

  dim3 blk(256);
  k_decode     <<<dim3((N_ANCH * 4 + 255) / 256), blk, 0, stream>>>(ps, pm, pl, anch, ws);
  k_selcomp    <<<dim3(1), dim3(1024), 0, stream>>>(ws);
  k_rankscatter<<<dim3((N_ANCH + 255) / 256), blk, 0, stream>>>(ws, out);
  k_iou        <<<dim3(LTILES), blk, 0, stream>>>(ws);
  k_nms        <<<dim3(1), dim3(64), 0, stream>>>(ws, out);
}

// Round 9
// 147.093 us; speedup vs baseline: 1.6956x; 1.0921x over previous
//
#include <hip/hip_runtime.h>
#include <cstdint>
#include <cstddef>

#define N_ANCH 25200
#define NB0 19200
#define NB1 24000
#define TOPK_N 4096
#define CONF_T 0.001
#define NMS_T 0.6
#define IMGS 640.0
#define NBINS 4096       // fp32 bits >> 18 (score in [0,1] -> bin <= 4064)
#define LTILES 544       // lower-triangle (ti,w) tiles: sum_{ti=0}^{15} (4*ti+4)

typedef unsigned long long u64;

struct WS {
  alignas(64) double sc[N_ANCH];       // masked score (sc or -1.0)
  alignas(64) double box[N_ANCH][4];   // clipped normalized boxes, fp64
  alignas(64) int    cls[N_ANCH];
  alignas(64) int    binv[N_ANCH];     // score bin per anchor
  alignas(64) int    sid[N_ANCH];      // bin-grouped compacted anchor ids
  alignas(64) double ssc[N_ANCH];      // bin-grouped compacted scores
  alignas(64) int    sst[N_ANCH];      // bin segment start of this slot
  alignas(64) int    sen[N_ANCH];      // bin segment end of this slot
  int    m_count;
  alignas(64) double tbox[TOPK_N][4];
  alignas(64) double tarea[TOPK_N];
  alignas(64) double tsc[TOPK_N];
  alignas(64) int    tcls[TOPK_N];
  alignas(64) u64    supT[TOPK_N * 64]; // supT[i*64+w] written only for w <= i>>6 (rest stays poison; k_nms masks)
  alignas(64) u64    hasSup[64];        // bit i of word (i>>6): row i has >=1 suppressor
};

__device__ __forceinline__ double dsigmoid(double x) { return 1.0 / (1.0 + exp(-x)); }

__device__ __forceinline__ int score_bin(double sc) {
  if (sc < 0.0) return 0;                          // masked
  return (int)(__float_as_uint((float)sc) >> 18);  // monotone for positive floats
}

// 4 lanes per anchor: lane r of a team handles classes c ≡ r (mod 4).
__global__ void k_decode(const float* __restrict__ ps, const float* __restrict__ pm,
                         const float* __restrict__ pl, const float* __restrict__ anch,
                         WS* __restrict__ ws) {
  int tid = blockIdx.x * 256 + threadIdx.x;
  if (tid < 64) ws->hasSup[tid] = 0ull;   // zero for k_iou's atomicOr
  int a = tid >> 2;
  int r = tid & 3;
  if (a >= N_ANCH) return;   // team-uniform (4-aligned)
  const float* p; int W, base, lvl; double stride;
  if (a < NB0)      { p = ps; W = 80; base = 0;   lvl = 0; stride = 8.0; }
  else if (a < NB1) { p = pm; W = 40; base = NB0; lvl = 1; stride = 16.0; }
  else              { p = pl; W = 20; base = NB1; lvl = 2; stride = 32.0; }
  int e = a - base;
  int pos = e / 3;
  int k = e - 3 * pos;
  int HW = W * W;

  // class max/argmax + softmax denom, 20 classes per lane
  const float* pc = p + (size_t)(3 + k * 80) * HW + pos;
  double m = -1e300, ssum = 0.0; int am = 0;
  for (int t = 0; t < 20; ++t) {
    int c = r + 4 * t;
    double v = (double)pc[(size_t)c * HW];
    ssum += exp(v);
    if (v > m) { m = v; am = c; }  // strict > keeps first occurrence per lane
  }
  // team reduction (lanes r^1, r^2 are in the same 4-lane group within the wave)
  for (int off = 1; off <= 2; off <<= 1) {
    double om = __shfl_xor(m, off);
    int oam   = __shfl_xor(am, off);
    double os = __shfl_xor(ssum, off);
    ssum += os;
    if (om > m || (om == m && oam < am)) { m = om; am = oam; }  // first-max tie-break
  }

  if (r == 0) {
    double sobj = dsigmoid((double)p[(size_t)k * HW + pos]);
    double sc = sobj * (exp(m) / ssum);

    int x = pos % W, y = pos / W;
    const float* pr = p + (size_t)(243 + k * 4) * HW + pos;
    double tx = (double)pr[0];
    double ty = (double)pr[(size_t)HW];
    double tw = (double)pr[(size_t)2 * HW];
    double th = (double)pr[(size_t)3 * HW];
    double cx = (dsigmoid(tx) + (double)x) * stride;
    double cy = (dsigmoid(ty) + (double)y) * stride;
    double aw = (double)anch[lvl * 6 + k * 2 + 0];
    double ah = (double)anch[lvl * 6 + k * 2 + 1];
    double bw = exp(tw) * aw;
    double bh = exp(th) * ah;
    double x1 = fmin(fmax((cx - 0.5 * bw) / IMGS, 0.0), 1.0);
    double y1 = fmin(fmax((cy - 0.5 * bh) / IMGS, 0.0), 1.0);
    double x2 = fmin(fmax((cx + 0.5 * bw) / IMGS, 0.0), 1.0);
    double y2 = fmin(fmax((cy + 0.5 * bh) / IMGS, 0.0), 1.0);

    ws->box[a][0] = x1; ws->box[a][1] = y1;
    ws->box[a][2] = x2; ws->box[a][3] = y2;
    ws->cls[a] = am;
    double scm = (sc >= CONF_T) ? sc : -1.0;
    ws->sc[a] = scm;
    ws->binv[a] = score_bin(scm);
  }
}

// single block: LDS hist -> t_bin = max b with S(b)=#{bin>=b} >= TOPK_N,
// then BIN-GROUPED compaction: slot = off0[bin] + within-bin counter.
// Global rank of a slot later = sst + exact rank within its bin segment.
__global__ void __launch_bounds__(1024) k_selcomp(WS* __restrict__ ws) {
  __shared__ int hist[NBINS];   // 16 KB
  __shared__ int off0[NBINS];   // 16 KB  (count of elements in strictly higher bins)
  __shared__ int cnt[NBINS];    // 16 KB  (within-bin compaction counters)
  __shared__ int part[1024];
  __shared__ int s_tbin;
  int t = threadIdx.x;
  for (int i = t; i < NBINS; i += 1024) { hist[i] = 0; cnt[i] = 0; }
  __syncthreads();
  for (int i = t; i < N_ANCH; i += 1024) atomicAdd(&hist[ws->binv[i]], 1);
  __syncthreads();
  const int CH = NBINS / 1024;  // 4 reversed bins per thread
  int sum = 0;
  for (int rr = 0; rr < CH; ++rr) sum += hist[NBINS - 1 - (t * CH + rr)];
  part[t] = sum;
  __syncthreads();
  for (int off = 1; off < 1024; off <<= 1) {
    int v = (t >= off) ? part[t - off] : 0;
    __syncthreads();
    part[t] += v;
    __syncthreads();
  }
  int cum = part[t] - sum;  // count in bins above this thread's chunk
  for (int rr = 0; rr < CH; ++rr) {
    int b = NBINS - 1 - (t * CH + rr);
    int h = hist[b];
    off0[b] = cum;
    int prev = cum;
    cum += h;
    if (prev < TOPK_N && cum >= TOPK_N) { s_tbin = b; ws->m_count = cum; }  // unique
  }
  __syncthreads();
  int tbin = s_tbin;
  for (int i = t; i < N_ANCH; i += 1024) {
    int b = ws->binv[i];
    if (b >= tbin) {
      int w = atomicAdd(&cnt[b], 1);
      int slot = off0[b] + w;
      ws->sid[slot] = i;
      ws->ssc[slot] = ws->sc[i];
      ws->sst[slot] = off0[b];
      ws->sen[slot] = off0[b] + hist[b];
    }
  }
}

// rank = sst + #{j in own bin segment : sc_j > sc_i or (sc_j==sc_i && aj<ai)}.
// The block's 256 slots span a CONTIGUOUS j-range [sst(first), sen(last))
// (bin-grouped order => st/en monotone in slot). Stage that range through LDS
// in coalesced 2048-chunks; each thread scans only its own segment's
// intersection with the chunk (LDS-speed compares, ~3 cyc/iter, vs the R8
// serial global-latency loop that cost 41 us at 0.4% occupancy).
__global__ void k_rankscatter(WS* __restrict__ ws, float* __restrict__ out) {
  const int CHUNK = 2048;
  __shared__ double sj[CHUNK];
  __shared__ int    aj[CHUNK];
  __shared__ int s_j0, s_j1;
  int m = ws->m_count;
  int b0 = blockIdx.x * 256;
  if (b0 >= m) return;   // block-uniform exit
  int t = threadIdx.x;
  int i = b0 + t;
  bool active = (i < m);
  if (t == 0) {
    s_j0 = ws->sst[b0];
    s_j1 = ws->sen[min(m - 1, b0 + 255)];
  }
  int ai = active ? ws->sid[i] : 0;
  double si = active ? ws->ssc[i] : 0.0;
  int st = active ? ws->sst[i] : 0;
  int en = active ? ws->sen[i] : 0;
  __syncthreads();
  int j0 = s_j0, j1 = s_j1;

  int cnt = 0;
  for (int jc = j0; jc < j1; jc += CHUNK) {
    int n = min(CHUNK, j1 - jc);
    __syncthreads();   // previous chunk fully consumed before overwrite
    for (int u = t; u < n; u += 256) {
      sj[u] = ws->ssc[jc + u];
      aj[u] = ws->sid[jc + u];
    }
    __syncthreads();
    int lo = max(st, jc) - jc;
    int hi = min(en, jc + n) - jc;
    for (int u = lo; u < hi; ++u) {
      double s = sj[u];
      cnt += (int)((s > si) | ((s == si) & (aj[u] < ai)));
    }
  }

  int r = st + cnt;
  if (active && r < TOPK_N) {
    double b0d = ws->box[ai][0], b1 = ws->box[ai][1];
    double b2 = ws->box[ai][2], b3 = ws->box[ai][3];
    int    c  = ws->cls[ai];
    ws->tbox[r][0] = b0d; ws->tbox[r][1] = b1;
    ws->tbox[r][2] = b2;  ws->tbox[r][3] = b3;
    ws->tarea[r] = (b2 - b0d) * (b3 - b1);
    ws->tsc[r] = si;
    ws->tcls[r] = c;
    out[r * 4 + 0] = (float)b0d;
    out[r * 4 + 1] = (float)b1;
    out[r * 4 + 2] = (float)b2;
    out[r * 4 + 3] = (float)b3;
    out[4 * TOPK_N + r] = (float)si;
    out[5 * TOPK_N + r] = (float)c;
  }
}

// Lower-triangle suppression tiles ONLY (544 blocks). Tile (ti,w): rows
// i in [ti*256, ti*256+256), cols j in [w*64, w*64+64), w <= 4*ti+3.
// supT[i*64+w] bit u: j=w*64+u suppresses i (same class, iou>0.6, j<i).
__global__ void __launch_bounds__(256) k_iou(WS* __restrict__ ws) {
  __shared__ double jb[64][5];
  __shared__ int jc[64];
  int t = threadIdx.x;
  int bx = blockIdx.x;
  // invert triangular numbering: tiles before ti = 2*ti*(ti+1)
  int ti = (int)((sqrtf(2.0f * (float)bx + 1.0f) - 1.0f) * 0.5f);
  while (2 * (ti + 1) * (ti + 2) <= bx) ++ti;
  while (2 * ti * (ti + 1) > bx) --ti;
  int w = bx - 2 * ti * (ti + 1);
  int i0 = ti * 256, jbase = w * 64;

  if (t < 64) {
    int j = jbase + t;
    jb[t][0] = ws->tbox[j][0];
    jb[t][1] = ws->tbox[j][1];
    jb[t][2] = ws->tbox[j][2];
    jb[t][3] = ws->tbox[j][3];
    jb[t][4] = ws->tarea[j];
    jc[t] = ws->tcls[j];
  }
  __syncthreads();
  int i = i0 + t;
  double x1 = ws->tbox[i][0], y1 = ws->tbox[i][1];
  double x2 = ws->tbox[i][2], y2 = ws->tbox[i][3];
  double ai = ws->tarea[i];
  int ci = ws->tcls[i];
  u64 bits = 0;
  for (int u = 0; u < 64; ++u) {
    double xx1 = fmax(x1, jb[u][0]);
    double yy1 = fmax(y1, jb[u][1]);
    double xx2 = fmin(x2, jb[u][2]);
    double yy2 = fmin(y2, jb[u][3]);
    double iw = fmax(1e-28, xx2 - xx1);
    double ih = fmax(1e-28, yy2 - yy1);
    double inter = iw * ih;
    double denom = ai + jb[u][4] - inter + 1e-14;
    bool sup = (jc[u] == ci) && (inter > NMS_T * denom) && ((jbase + u) < i);
    bits |= ((u64)sup) << u;
  }
  ws->supT[(size_t)i * 64 + w] = bits;
  if (bits) atomicOr(&ws->hasSup[i >> 6], 1ull << (i & 63));
}

// single-wave greedy scan over CONTESTED candidates only. Row loads are
// UNCONDITIONAL (batched prefetch); upper-triangle words contain workspace
// poison and are masked out per-lane AFTER the load (lane <= i>>6).
__global__ void __launch_bounds__(64) k_nms(const WS* __restrict__ ws, float* __restrict__ out) {
  __shared__ u64 hsArr[64];
  __shared__ int lst[TOPK_N];
  int lane = threadIdx.x;

  u64 validw = 0;
  const double4* tp = (const double4*)(ws->tsc + lane * 64);
  for (int q = 0; q < 16; ++q) {
    double4 v = tp[q];
    validw |= ((u64)(v.x >= CONF_T)) << (q * 4 + 0);
    validw |= ((u64)(v.y >= CONF_T)) << (q * 4 + 1);
    validw |= ((u64)(v.z >= CONF_T)) << (q * 4 + 2);
    validw |= ((u64)(v.w >= CONF_T)) << (q * 4 + 3);
  }

  u64 hasw = ws->hasSup[lane];
  u64 keepw = validw & ~hasw;   // bulk-keep uncontested valid candidates
  hsArr[lane] = hasw;
  __syncthreads();

  int K = 0;
  for (int l = 0; l < 64; ++l) {
    u64 w = hsArr[l];
    while (w) {
      int b = __builtin_ctzll(w);
      w &= w - 1;
      if (lane == 0) lst[K] = l * 64 + b;
      ++K;
    }
  }
  __syncthreads();

  const u64* ST = ws->supT;
  int IA[16], IB[16];
  u64 A[16], B[16];

  // post-load mask: lane holds valid word only if lane <= i>>6
#define RB(BUF, IDX) ((lane <= ((IDX) >> 6)) ? BUF : 0ull)

#pragma unroll
  for (int r = 0; r < 16; ++r) IA[r] = (r < K) ? lst[r] : 0;
#pragma unroll
  for (int r = 0; r < 16; ++r) A[r] = (r < K) ? ST[(size_t)IA[r] * 64 + lane] : 0ull;

  for (int base = 0; base < K; base += 32) {
#pragma unroll
    for (int r = 0; r < 16; ++r) IB[r] = (base + 16 + r < K) ? lst[base + 16 + r] : 0;
#pragma unroll
    for (int r = 0; r < 16; ++r) B[r] = (base + 16 + r < K) ? ST[(size_t)IB[r] * 64 + lane] : 0ull;
#pragma unroll
    for (int r = 0; r < 16; ++r) {
      if (base + r < K) {
        int i = IA[r];
        u64 bal = __ballot((keepw & RB(A[r], i)) != 0ull);
        if (lane == (i >> 6) && bal == 0ull && ((validw >> (i & 63)) & 1ull))
          keepw |= 1ull << (i & 63);
      }
    }
#pragma unroll
    for (int r = 0; r < 16; ++r) IA[r] = (base + 32 + r < K) ? lst[base + 32 + r] : 0;
#pragma unroll
    for (int r = 0; r < 16; ++r) A[r] = (base + 32 + r < K) ? ST[(size_t)IA[r] * 64 + lane] : 0ull;
#pragma unroll
    for (int r = 0; r < 16; ++r) {
      if (base + 16 + r < K) {
        int i = IB[r];
        u64 bal = __ballot((keepw & RB(B[r], i)) != 0ull);
        if (lane == (i >> 6) && bal == 0ull && ((validw >> (i & 63)) & 1ull))
          keepw |= 1ull << (i & 63);
      }
    }
  }
#undef RB

  for (int b = 0; b < 64; ++b)
    out[6 * TOPK_N + lane * 64 + b] = (float)((keepw >> b) & 1ull);
}

extern "C" void kernel_launch(void* const* d_in, const int* in_sizes, int n_in,
                              void* d_out, int out_size, void* d_ws, size_t ws_size,
                              hipStream_t stream) {
  const float* ps   = (const float*)d_in[0];
  const float* pm   = (const float*)d_in[1];
  const float* pl   = (const float*)d_in[2];
  const float* anch = (const float*)d_in[3];
  float* out = (float*)d_out;
  WS* ws = (WS*)d_ws;

  dim3 blk(256);
  k_decode     <<<dim3((N_ANCH * 4 + 255) / 256), blk, 0, stream>>>(ps, pm, pl, anch, ws);
  k_selcomp    <<<dim3(1), dim3(1024), 0, stream>>>(ws);
  k_rankscatter<<<dim3((N_ANCH + 255) / 256), blk, 0, stream>>>(ws, out);
  k_iou        <<<dim3(LTILES), blk, 0, stream>>>(ws);
  k_nms        <<<dim3(1), dim3(64), 0, stream>>>(ws, out);
}